// Round 1
// 1876.654 us; speedup vs baseline: 2.4279x; 2.4279x over previous
//
#include <hip/hip_runtime.h>

// Persistent 2-layer LSTM, T=512, B=64, H=512. fp32 in/out, bf16 MFMA.
// Batch split into 4 independent groups of 16 rows (batch rows are
// independent recurrent chains). Grid = 256 blocks: bid = l*128 + g*32 + bb.
// Domain (l,g) = 32 blocks exchanging a 16x512 bf16 h-tile via L3
// (sc0 sc1 loads/stores). Per-BLOCK flags (32 dwords = 2 lines per domain),
// published after vmcnt(0)+barrier. Layer1 polls both domains in one loop
// and loads h1||h0 in one vmcnt batch (removes one serial round trip).

#define T_SEQ 512

typedef short s16x8 __attribute__((ext_vector_type(8)));
typedef int   i32x4 __attribute__((ext_vector_type(4)));
typedef float f32x4 __attribute__((ext_vector_type(4)));

__device__ __forceinline__ short f2bf(float f) {
    unsigned u = __builtin_bit_cast(unsigned, f);
    unsigned r = (u + 0x7fffu + ((u >> 16) & 1u)) >> 16;   // RNE
    return (short)r;
}
__device__ __forceinline__ float sigf(float x) { return 1.0f / (1.0f + __expf(-x)); }
__device__ __forceinline__ float tanhff(float x) { return 2.0f * sigf(2.0f * x) - 1.0f; }

// ---- setup: cast x (fp32) -> bf16 ----
__global__ __launch_bounds__(256) void xcast_kernel(const float* __restrict__ x,
                                                    short* __restrict__ xb) {
    int i = (blockIdx.x * 256 + threadIdx.x) * 8;
    float4 a = *(const float4*)(x + i);
    float4 b = *(const float4*)(x + i + 4);
    s16x8 v;
    v[0]=f2bf(a.x); v[1]=f2bf(a.y); v[2]=f2bf(a.z); v[3]=f2bf(a.w);
    v[4]=f2bf(b.x); v[5]=f2bf(b.y); v[6]=f2bf(b.z); v[7]=f2bf(b.w);
    *(s16x8*)(xb + i) = v;
}

// ---- setup: pack weights [l][bb][w][g][kk0..7][lane][8] bf16 (unchanged) ----
// wave w: kk 0..3 -> input half (Wxh), kk 4..7 -> recurrent half (Whh),
//         k = w*128 + (kk&3)*32 + (lane>>4)*8 ; col j' = g*512 + bb*16 + (lane&15)
__global__ __launch_bounds__(256) void wpack_kernel(const float* __restrict__ Wxh,
                                                    const float* __restrict__ Whh,
                                                    short* __restrict__ wp) {
    int fg = blockIdx.x * 256 + threadIdx.x;        // [0, 524288)
    int lane = fg & 63;
    int kk   = (fg >> 6)  & 7;
    int g    = (fg >> 9)  & 3;
    int w    = (fg >> 11) & 3;
    int bb   = (fg >> 13) & 31;
    int l    = (fg >> 18) & 1;
    int ksrc = w * 128 + (kk & 3) * 32 + (lane >> 4) * 8;
    int jp   = g * 512 + bb * 16 + (lane & 15);
    const float* src = (kk < 4) ? (Wxh + ((size_t)(l * 2048 + jp) * 512 + ksrc))
                                : (Whh + ((size_t)(l * 2048 + jp) * 512 + ksrc));
    float4 a = *(const float4*)src;
    float4 b = *(const float4*)(src + 4);
    s16x8 v;
    v[0]=f2bf(a.x); v[1]=f2bf(a.y); v[2]=f2bf(a.z); v[3]=f2bf(a.w);
    v[4]=f2bf(b.x); v[5]=f2bf(b.y); v[6]=f2bf(b.z); v[7]=f2bf(b.w);
    *(s16x8*)(wp + (size_t)fg * 8) = v;
}

// ---- coherent (L3) 4-frag load: af[kk], one 16-row tile slice ----
__device__ __forceinline__ void load4_c(i32x4 af[4], const short* base) {
    asm volatile(
        "global_load_dwordx4 %0, %4, off sc0 sc1\n\t"
        "global_load_dwordx4 %1, %4, off offset:64 sc0 sc1\n\t"
        "global_load_dwordx4 %2, %4, off offset:128 sc0 sc1\n\t"
        "global_load_dwordx4 %3, %4, off offset:192 sc0 sc1\n\t"
        "s_waitcnt vmcnt(0)"
        : "=&v"(af[0]), "=&v"(af[1]), "=&v"(af[2]), "=&v"(af[3])
        : "v"(base)
        : "memory");
}

// ---- coherent 8-frag load: recurrent (b0) + input (b1) in one vmcnt batch ----
__device__ __forceinline__ void load8_c(i32x4 ar[4], i32x4 ai[4],
                                        const short* b0, const short* b1) {
    asm volatile(
        "global_load_dwordx4 %0, %8, off sc0 sc1\n\t"
        "global_load_dwordx4 %1, %8, off offset:64 sc0 sc1\n\t"
        "global_load_dwordx4 %2, %8, off offset:128 sc0 sc1\n\t"
        "global_load_dwordx4 %3, %8, off offset:192 sc0 sc1\n\t"
        "global_load_dwordx4 %4, %9, off sc0 sc1\n\t"
        "global_load_dwordx4 %5, %9, off offset:64 sc0 sc1\n\t"
        "global_load_dwordx4 %6, %9, off offset:128 sc0 sc1\n\t"
        "global_load_dwordx4 %7, %9, off offset:192 sc0 sc1\n\t"
        "s_waitcnt vmcnt(0)"
        : "=&v"(ar[0]), "=&v"(ar[1]), "=&v"(ar[2]), "=&v"(ar[3]),
          "=&v"(ai[0]), "=&v"(ai[1]), "=&v"(ai[2]), "=&v"(ai[3])
        : "v"(b0), "v"(b1)
        : "memory");
}

// ---- merged wait: all 32 block-flags of fa >= ta AND fb >= tb, one loop ----
__device__ __forceinline__ void waitf2(const unsigned* fa, int ta,
                                       const unsigned* fb, int tb, int lane) {
    if (ta <= 0 && tb <= 0) return;
    const unsigned* pa = fa + (lane & 31);
    const unsigned* pb = fb + (lane & 31);
    int v0, v1;
    do {
        asm volatile("global_load_dword %0, %2, off sc0 sc1\n\t"
                     "global_load_dword %1, %3, off sc0 sc1\n\t"
                     "s_waitcnt vmcnt(0)"
                     : "=&v"(v0), "=&v"(v1)
                     : "v"(pa), "v"(pb) : "memory");
    } while (v0 < ta || v1 < tb);
}

__global__ __launch_bounds__(256, 1) void lstm_persist(
    const short* __restrict__ xb,    // [T][64][512] bf16
    const short* __restrict__ wp,    // packed weights
    short* __restrict__ h0r,         // [8][64][512] bf16 ring (slot s = h0[s-1])
    short* __restrict__ h1r,         // [8][64][512] bf16 ring
    const float* __restrict__ bxh,   // [2][2048]
    const float* __restrict__ bhh,   // [2][2048]
    float* __restrict__ out,         // T*B*H | hT[2,B,H] | cT[2,B,H]
    unsigned* flags) {               // [2 layers][4 groups][32 blocks]

    const int l    = blockIdx.x >> 7;        // layer
    const int g    = (blockIdx.x >> 5) & 3;  // batch group (rows g*16..g*16+15)
    const int bb   = blockIdx.x & 31;        // col block (16 h-cols)
    const int tid  = threadIdx.x;
    const int wv   = tid >> 6;
    const int lane = tid & 63;

    __shared__ float red[16 * 288];  // [wv*4+g4][row:16, stride 18] (+col 16)

    // ---- weights into registers (once; shared across groups -> (l,bb) index) ----
    s16x8 breg[4][8];
    {
        const short* wb = wp + (size_t)((l * 32 + bb) * 4 + wv) * 16384 + lane * 8;
        #pragma unroll
        for (int g4 = 0; g4 < 4; ++g4)
            #pragma unroll
            for (int kk = 0; kk < 8; ++kk)
                breg[g4][kk] = *(const s16x8*)(wb + (g4 * 8 + kk) * 512);
    }

    // ---- epilogue constants: thread owns 1 cell (row em, col ec) ----
    const int em = tid >> 4;        // 0..15 (row within group)
    const int ec = tid & 15;        // 0..15 (col within block)
    const int ej = bb * 16 + ec;    // h-col / gate-col within 512
    float bsum[4];
    #pragma unroll
    for (int g4 = 0; g4 < 4; ++g4)
        bsum[g4] = bxh[l * 2048 + g4 * 512 + ej] + bhh[l * 2048 + g4 * 512 + ej];

    float creg = 0.f;

    const int arow  = lane & 15;
    const int acol  = wv * 128 + (lane >> 4) * 8;     // + kk*32 (as 64 B asm offsets)
    const int aboff = (g * 16 + arow) * 512 + acol;

    const unsigned* fown = flags + (l * 4 + g) * 32;
    const unsigned* foth = flags + ((1 - l) * 4 + g) * 32;
    unsigned* myflag = flags + (l * 4 + g) * 32 + bb;

    for (int t = 0; t < T_SEQ; ++t) {
        f32x4 acc[4];
        #pragma unroll
        for (int g4 = 0; g4 < 4; ++g4)
            acc[g4] = (f32x4){0.f, 0.f, 0.f, 0.f};

        if (l == 0) {
            // input half = x[t]: no wait, normal cached loads (hides latency)
            const short* ab = xb + (size_t)t * 32768 + aboff;
            s16x8 ax[4];
            #pragma unroll
            for (int kk = 0; kk < 4; ++kk)
                ax[kk] = *(const s16x8*)(ab + kk * 32);
            #pragma unroll
            for (int kk = 0; kk < 4; ++kk)
                #pragma unroll
                for (int g4 = 0; g4 < 4; ++g4)
                    acc[g4] = __builtin_amdgcn_mfma_f32_16x16x32_bf16(
                        ax[kk], breg[g4][kk], acc[g4], 0, 0, 0);
            // merged wait: own domain >= t, l1 backpressure >= t-7
            waitf2(fown, t, foth, t - 7, lane);
            i32x4 af[4];
            load4_c(af, h0r + (size_t)(t & 7) * 32768 + aboff);
            #pragma unroll
            for (int kk = 0; kk < 4; ++kk)
                #pragma unroll
                for (int g4 = 0; g4 < 4; ++g4)
                    acc[g4] = __builtin_amdgcn_mfma_f32_16x16x32_bf16(
                        __builtin_bit_cast(s16x8, af[kk]),
                        breg[g4][4 + kk], acc[g4], 0, 0, 0);
        } else {
            // merged wait: h1[t-1] (own >= t) AND h0[t] (producer >= t+1)
            waitf2(fown, t, foth, t + 1, lane);
            i32x4 af[4], ag[4];
            load8_c(af, ag, h1r + (size_t)(t & 7) * 32768 + aboff,
                            h0r + (size_t)((t + 1) & 7) * 32768 + aboff);
            #pragma unroll
            for (int kk = 0; kk < 4; ++kk)
                #pragma unroll
                for (int g4 = 0; g4 < 4; ++g4)
                    acc[g4] = __builtin_amdgcn_mfma_f32_16x16x32_bf16(
                        __builtin_bit_cast(s16x8, af[kk]),
                        breg[g4][4 + kk], acc[g4], 0, 0, 0);
            #pragma unroll
            for (int kk = 0; kk < 4; ++kk)
                #pragma unroll
                for (int g4 = 0; g4 < 4; ++g4)
                    acc[g4] = __builtin_amdgcn_mfma_f32_16x16x32_bf16(
                        __builtin_bit_cast(s16x8, ag[kk]),
                        breg[g4][kk], acc[g4], 0, 0, 0);
        }

        // ---- cross-wave K-reduction (stride 18 -> 2-way banks, free) ----
        #pragma unroll
        for (int g4 = 0; g4 < 4; ++g4)
            #pragma unroll
            for (int q = 0; q < 4; ++q)
                red[(wv * 4 + g4) * 288
                    + ((lane >> 4) * 4 + q) * 18 + (lane & 15)] = acc[g4][q];
        __syncthreads();

        // ---- epilogue: 1 cell per thread ----
        float cg[4];
        #pragma unroll
        for (int g4 = 0; g4 < 4; ++g4) {
            float s = bsum[g4];
            #pragma unroll
            for (int w = 0; w < 4; ++w)
                s += red[(w * 4 + g4) * 288 + em * 18 + ec];
            cg[g4] = s;
        }

        float cn = sigf(cg[1]) * creg + sigf(cg[0]) * tanhff(cg[2]);
        float hv = sigf(cg[3]) * tanhff(cn);
        creg = cn;

        // h ring store (coherent, write-through to L3)
        {
            short* hring = (l == 0) ? h0r : h1r;
            short* hp = hring + (size_t)((t + 1) & 7) * 32768
                      + (g * 16 + em) * 512 + ej;
            int hb = (int)(unsigned short)f2bf(hv);
            asm volatile("global_store_short %0, %1, off sc0 sc1"
                         :: "v"(hp), "v"(hb) : "memory");
        }
        // normal cached output stores
        if (l == 1)
            out[(size_t)t * 32768 + (size_t)(g * 16 + em) * 512 + ej] = hv;
        if (t == T_SEQ - 1) {
            size_t base = (size_t)T_SEQ * 32768;
            out[base + (size_t)(l * 64 + g * 16 + em) * 512 + ej] = hv;
            out[base + 65536 + (size_t)(l * 64 + g * 16 + em) * 512 + ej] = creg;
        }

        // drain sc1 stores, join waves, publish ONE per-block flag
        asm volatile("s_waitcnt vmcnt(0)" ::: "memory");
        __syncthreads();
        if (tid == 0) {
            int fv = t + 1;
            asm volatile("global_store_dword %0, %1, off sc0 sc1"
                         :: "v"(myflag), "v"(fv) : "memory");
        }
    }
}

extern "C" void kernel_launch(void* const* d_in, const int* in_sizes, int n_in,
                              void* d_out, int out_size, void* d_ws, size_t ws_size,
                              hipStream_t stream) {
    const float* x   = (const float*)d_in[0];
    const float* Wxh = (const float*)d_in[1];
    const float* Whh = (const float*)d_in[2];
    const float* bxh = (const float*)d_in[3];
    const float* bhh = (const float*)d_in[4];
    float* out = (float*)d_out;

    char* ws = (char*)d_ws;
    short*    xb    = (short*)(ws);                     // 33,554,432 B
    short*    wpk   = (short*)(ws + 33554432);          //  8,388,608 B
    short*    h0r   = (short*)(ws + 41943040);          //    524,288 B
    short*    h1r   = (short*)(ws + 42467328);          //    524,288 B
    unsigned* flags = (unsigned*)(ws + 42991616);       //      1,024 B

    // zero rings + flags (ws re-poisoned 0xAA before every timed launch)
    hipMemsetAsync(ws + 41943040, 0, 1049600, stream);

    xcast_kernel<<<dim3(8192), dim3(256), 0, stream>>>(x, xb);
    wpack_kernel<<<dim3(2048), dim3(256), 0, stream>>>(Wxh, Whh, wpk);

    lstm_persist<<<dim3(256), dim3(256), 0, stream>>>(xb, wpk, h0r, h1r,
                                                      bxh, bhh, out, flags);
}